// Round 7
// baseline (265.494 us; speedup 1.0000x reference)
//
#include <hip/hip_runtime.h>
#include <hip/hip_bf16.h>

// EMAVectorQuantizer: B=8, D=256, T=1024, BT=8192, N=16384
// Outputs (FLOAT32, concat): out[B,D,T], perplexity, idx[BT], loss,
// new_weight[N,D], new_cluster_size[N], new_embed_avg[N,D] = 10,510,338 f32

#define B_ 8
#define D_ 256
#define T_ 1024
#define BT_ 8192
#define N_ 16384

// d_out element offsets (float32 elements)
#define O_OUT   0
#define O_PERP  2097152
#define O_IDX   2097153
#define O_LOSS  2105345
#define O_NEWW  2105346
#define O_NCS   6299650
#define O_NEA   6316034

// workspace byte offsets (ends ~21.2 MiB; prior session verified ws >= 25 MB)
#define W_CNT   0ull        // counts[N] f32 (zeroed)
#define W_SCAL  65536ull    // scalars: [0]=loss_sum [1]=ent [2]=ntot (zeroed)
#define W_W2    98560ull    // w2[N] f32
#define W_IDXI  164096ull   // idx int32[BT]
#define W_PACK  196864ull   // pack[BT][16] u64 candidates (1 MB, fully written)
#define W_ZH    1245440ull  // zh[BT][D] fp16, transposed z (4 MB)
#define W_WH    5439744ull  // wh[N][D] fp16 (8 MB)
#define W_ZT    13828352ull // zt[BT][D] f32, transposed z (8 MB) for exact re-rank

typedef __attribute__((ext_vector_type(8))) _Float16 half8;
typedef __attribute__((ext_vector_type(4))) _Float16 half4;
typedef __attribute__((ext_vector_type(4))) float f32x4;

__device__ __forceinline__ void gl_lds(const void* g, void* l) {
  __builtin_amdgcn_global_load_lds(
      (const __attribute__((address_space(1))) unsigned int*)g,
      (__attribute__((address_space(3))) unsigned int*)l, 16, 0, 0);
}

// monotone unsigned key for float compare (handles negative d = w2/2 - dot)
__device__ __forceinline__ unsigned sortable(float f) {
  unsigned u = __float_as_uint(f);
  return u ^ (((unsigned)((int)u >> 31)) | 0x80000000u);
}

// ---- prep z: transpose to zh fp16 + zt f32; fused new_embed_avg init ----
__global__ void k_prepz_r14(const float* __restrict__ z, _Float16* __restrict__ zh,
                            float* __restrict__ zt, const float* __restrict__ ea,
                            float* __restrict__ onea) {
  __shared__ float tile[64][65];
  const int t0 = blockIdx.x << 6, d0 = blockIdx.y << 6, b = blockIdx.z;
  const int tt = threadIdx.x & 63, q = threadIdx.x >> 6;
  for (int i = 0; i < 16; ++i) {
    const int dd = q + (i << 2);
    tile[tt][dd] = z[((size_t)b * D_ + d0 + dd) * T_ + t0 + tt];
  }
  // fused: onea = 0.99*ea (512 blocks x 256 thr x 8 float4 = N*D floats)
  const int bid = blockIdx.x + (blockIdx.y << 4) + (blockIdx.z << 6);
  const float4* eav = reinterpret_cast<const float4*>(ea);
  float4* ov = reinterpret_cast<float4*>(onea);
#pragma unroll
  for (int i = 0; i < 8; ++i) {
    const int idx = (bid << 11) + (i << 8) + threadIdx.x;
    const float4 v = eav[idx];
    float4 o;
    o.x = 0.99f * v.x; o.y = 0.99f * v.y; o.z = 0.99f * v.z; o.w = 0.99f * v.w;
    ov[idx] = o;
  }
  __syncthreads();
  for (int i = 0; i < 16; ++i) {
    const int ttw = q + (i << 2);
    const float v = tile[ttw][tt];
    const size_t off = ((size_t)(b * T_ + t0 + ttw)) * D_ + d0 + tt;
    zh[off] = (_Float16)v;
    zt[off] = v;
  }
}

// ---- prep w: wh[N][D] fp16 + w2 (wave per row) ----
__global__ void k_prepw_r8(const float* __restrict__ w, _Float16* __restrict__ wh,
                           float* __restrict__ w2) {
  const int row = blockIdx.x * 4 + (threadIdx.x >> 6);
  const int lane = threadIdx.x & 63;
  const float4 v = reinterpret_cast<const float4*>(w + (size_t)row * D_)[lane];
  half4 h;
  h[0] = (_Float16)v.x; h[1] = (_Float16)v.y; h[2] = (_Float16)v.z; h[3] = (_Float16)v.w;
  *reinterpret_cast<half4*>(wh + (size_t)row * D_ + (lane << 2)) = h;
  float s = v.x * v.x + v.y * v.y + v.z * v.z + v.w * v.w;
  for (int o = 32; o; o >>= 1) s += __shfl_xor(s, o);
  if (lane == 0) w2[row] = s;
}

// ---- fp16 MFMA distance GEMM + top-2 per (row, 2048-col slice) ----
// grid (64 rowblocks of 128, 8 cy); 1024 thr = 16 waves (4 row-groups x 4
// col-groups), wave = 32 rows x 64 cols; ct = 8 col-tiles of 256.
// A-RESIDENT: the 128x256 A panel is staged ONCE (64 KB, 4 kc chunks), rounds
// stage only B (32 KB). Plain __syncthreads double-buffer on B.
// LDS swizzle: slot (m,c) holds source chunk c ^ (m&7).
__global__ __launch_bounds__(1024, 4) void k_dist_r14(
    const _Float16* __restrict__ zh, const _Float16* __restrict__ wh,
    const float* __restrict__ w2, unsigned long long* __restrict__ pack) {
  __shared__ _Float16 Asr[4][8192];   // resident A: 4 kc x (128 rows x 64 k) = 64 KB
  __shared__ _Float16 Bs[2][16384];   // B dbuf: 2 x (256 rows x 64 k) = 64 KB
  __shared__ unsigned long long Ms[4][128][2];  // cross-col-group merge (8 KB)

  const int tid = threadIdx.x;
  const int lane = tid & 63, w = tid >> 6;
  const int quad = lane >> 4, l15 = lane & 15;
  const int r0 = blockIdx.x << 7;
  const int cy = blockIdx.y;
  const int nbase = cy << 11;
  const int wrow = (w & 3) << 5;   // 4 row-groups x 32 rows
  const int wcol = (w >> 2) << 6;  // 4 col-groups x 64 cols

  // A staging: thread covers slot tid of each kc chunk (1024 slots/chunk)
  const int m_a = tid >> 3, cg_a = (tid & 7) ^ ((tid >> 3) & 7);
#pragma unroll
  for (int kc = 0; kc < 4; ++kc)
    gl_lds(zh + (((size_t)(r0 + m_a)) << 8) + (kc << 6) + (cg_a << 3),
           &Asr[kc][tid << 3]);

  // B staging geometry: thread covers slots tid and tid+1024 (2048 slots)
  int smb[2], scb[2];
#pragma unroll
  for (int j = 0; j < 2; ++j) {
    const int s = tid + (j << 10);
    smb[j] = s >> 3;
    scb[j] = (s & 7) ^ (smb[j] & 7);
  }
  // prologue: stage B(ct=0, kc=0) into buffer 0
#pragma unroll
  for (int j = 0; j < 2; ++j)
    gl_lds(wh + (((size_t)(nbase + smb[j])) << 8) + (scb[j] << 3),
           &Bs[0][(tid + (j << 10)) << 3]);

  float rd0[8], rd1[8];
  int ri0[8], ri1[8];
#pragma unroll
  for (int s = 0; s < 8; ++s) { rd0[s] = 3.0e38f; rd1[s] = 3.0e38f; ri0[s] = 0; ri1[s] = 0; }

  f32x4 acc[2][4];
  float w2h[4];

#pragma unroll 1
  for (int ct = 0; ct < 8; ++ct) {
    const int n0 = nbase + (ct << 8);
#pragma unroll
    for (int kc = 0; kc < 4; ++kc) {
      const int cur = kc & 1;  // static after unroll
      __syncthreads();
      if (kc < 3) {
        const int kb = (kc + 1) << 6;
#pragma unroll
        for (int j = 0; j < 2; ++j)
          gl_lds(wh + (((size_t)(n0 + smb[j])) << 8) + kb + (scb[j] << 3),
                 &Bs[cur ^ 1][(tid + (j << 10)) << 3]);
      } else if (ct < 7) {  // next ct, kc=0
        const int n0n = n0 + 256;
#pragma unroll
        for (int j = 0; j < 2; ++j)
          gl_lds(wh + (((size_t)(n0n + smb[j])) << 8) + (scb[j] << 3),
                 &Bs[cur ^ 1][(tid + (j << 10)) << 3]);
      }
      if (kc == 0) {
#pragma unroll
        for (int cf = 0; cf < 4; ++cf) w2h[cf] = 0.5f * w2[n0 + wcol + cf * 16 + l15];
#pragma unroll
        for (int i = 0; i < 2; ++i)
#pragma unroll
          for (int j = 0; j < 4; ++j) acc[i][j] = (f32x4)(0.f);
      }
#pragma unroll
      for (int kl = 0; kl < 2; ++kl) {  // 2 x K=32
        const int k8 = (kl << 2) + quad;
        half8 af[2], bf[4];
#pragma unroll
        for (int rf = 0; rf < 2; ++rf) {
          const int m = wrow + rf * 16 + l15;
          af[rf] = *reinterpret_cast<const half8*>(&Asr[kc][(m << 6) + ((k8 ^ (m & 7)) << 3)]);
        }
#pragma unroll
        for (int cf = 0; cf < 4; ++cf) {
          const int n = wcol + cf * 16 + l15;
          bf[cf] = *reinterpret_cast<const half8*>(&Bs[cur][(n << 6) + ((k8 ^ (n & 7)) << 3)]);
        }
#pragma unroll
        for (int rf = 0; rf < 2; ++rf)
#pragma unroll
          for (int cf = 0; cf < 4; ++cf)
            acc[rf][cf] = __builtin_amdgcn_mfma_f32_16x16x32_f16(af[rf], bf[cf], acc[rf][cf], 0, 0, 0);
      }
      if (kc == 3) {
        // key = w2/2 - dot (per-row z2/2 constant dropped; ordering unchanged)
#pragma unroll
        for (int rf = 0; rf < 2; ++rf)
#pragma unroll
          for (int cf = 0; cf < 4; ++cf) {
            const int idxv = n0 + wcol + cf * 16 + l15;
#pragma unroll
            for (int rg = 0; rg < 4; ++rg) {
              const int s = rf * 4 + rg;
              const float d = w2h[cf] - acc[rf][cf][rg];
              if (d < rd1[s]) {
                if (d < rd0[s]) { rd1[s] = rd0[s]; ri1[s] = ri0[s]; rd0[s] = d; ri0[s] = idxv; }
                else { rd1[s] = d; ri1[s] = idxv; }
              }
            }
          }
      }
    }
  }

  // merge top-2 across the 16 col-lanes of each quad (xor stays within quad).
#pragma unroll
  for (int s = 0; s < 8; ++s) {
    unsigned long long p0 = ((unsigned long long)sortable(rd0[s]) << 32) | (unsigned int)ri0[s];
    unsigned long long p1 = ((unsigned long long)sortable(rd1[s]) << 32) | (unsigned int)ri1[s];
    for (int off = 1; off < 16; off <<= 1) {
      const unsigned long long q0 = __shfl_xor(p0, off);
      const unsigned long long q1 = __shfl_xor(p1, off);
      const unsigned long long lo = p0 < q0 ? p0 : q0;
      const unsigned long long mx = p0 < q0 ? q0 : p0;
      const unsigned long long mn1 = p1 < q1 ? p1 : q1;
      p0 = lo;
      p1 = mx < mn1 ? mx : mn1;
    }
    if (l15 == 0) {
      const int row = wrow + (s >> 2) * 16 + quad * 4 + (s & 3);
      Ms[w >> 2][row][0] = p0;
      Ms[w >> 2][row][1] = p1;
    }
  }
  __syncthreads();
  // merge the four col-group slices -> top-2 per (row, cy)
  if (tid < 128) {
    unsigned long long p0 = Ms[0][tid][0], p1 = Ms[0][tid][1];
#pragma unroll
    for (int g = 1; g < 4; ++g) {
      const unsigned long long q0 = Ms[g][tid][0], q1 = Ms[g][tid][1];
      const unsigned long long n0_ = p0 < q0 ? p0 : q0;
      const unsigned long long n1_ = p0 < q0 ? (p1 < q0 ? p1 : q0) : (q1 < p0 ? q1 : p0);
      p0 = n0_;
      p1 = n1_;
    }
    unsigned long long* dst = pack + (((size_t)(r0 + tid)) << 4) + (cy << 1);
    dst[0] = p0;
    dst[1] = p1;
  }
}

// ---- fp64 re-rank of 16 candidates; idx + counts + loss + FUSED SCATTER ----
// wave per row; 4 x 16-lane groups re-rank 4 candidates each in parallel.
// After the argmin merge (wave-wide bestid), the wave scatters 0.01*z[row]
// into onea[bestid] directly from the zc registers it already loaded --
// replaces the separate k_scatter kernel (and its 32 MB z re-read).
__global__ void k_cand_r15(const float* __restrict__ zt, const float* __restrict__ weight,
                           const unsigned long long* __restrict__ pack,
                           int* __restrict__ idxi, float* __restrict__ counts,
                           float* __restrict__ oidx, float* __restrict__ loss_acc,
                           float* __restrict__ onea) {
  __shared__ float lred[4];
  const int wv_ = threadIdx.x >> 6;
  const int row = blockIdx.x * 4 + wv_;
  const int lane = threadIdx.x & 63;
  const int g = lane >> 4, l = lane & 15;

  float4 zc[4];
#pragma unroll
  for (int q = 0; q < 4; ++q)
    zc[q] = reinterpret_cast<const float4*>(zt + (size_t)row * D_)[(q << 4) + l];

  double best = 1.0e300;
  int bestid = 0x7FFFFFFF;
#pragma unroll
  for (int c = 0; c < 4; ++c) {
    const int cand = (int)(pack[((size_t)row << 4) + (g << 2) + c] & 0xFFFFFFFFull) & 16383;
    double s = 0.0;
#pragma unroll
    for (int q = 0; q < 4; ++q) {
      const float4 wvv = reinterpret_cast<const float4*>(weight + (size_t)cand * D_)[(q << 4) + l];
      const double d0 = (double)zc[q].x - (double)wvv.x;
      const double d1 = (double)zc[q].y - (double)wvv.y;
      const double d2 = (double)zc[q].z - (double)wvv.z;
      const double d3 = (double)zc[q].w - (double)wvv.w;
      s = fma(d0, d0, s); s = fma(d1, d1, s); s = fma(d2, d2, s); s = fma(d3, d3, s);
    }
    for (int o = 1; o < 16; o <<= 1) s += __shfl_xor(s, o);
    if (s < best || (s == best && cand < bestid)) { best = s; bestid = cand; }
  }
#pragma unroll
  for (int o = 16; o < 64; o <<= 1) {
    const double os = __shfl_xor(best, o);
    const int oi = __shfl_xor(bestid, o);
    if (os < best || (os == best && oi < bestid)) { best = os; bestid = oi; }
  }
  // fused scatter: group g covers d = g*64 + l*4 .. +3 with zc[g]
  {
    float* dst = onea + (size_t)bestid * D_ + (g << 6) + (l << 2);
    atomicAdd(dst + 0, 0.01f * zc[g].x);
    atomicAdd(dst + 1, 0.01f * zc[g].y);
    atomicAdd(dst + 2, 0.01f * zc[g].z);
    atomicAdd(dst + 3, 0.01f * zc[g].w);
  }
  if (lane == 0) {
    idxi[row] = bestid;
    oidx[row] = (float)bestid;
    atomicAdd(&counts[bestid], 1.0f);
    lred[wv_] = (float)best;
  }
  __syncthreads();
  if (threadIdx.x == 0)
    atomicAdd(loss_acc, lred[0] + lred[1] + lred[2] + lred[3]);
}

// ---------------- gather codebook rows -> out[B,D,T] (f32) ----------------
__global__ void k_gather_r8(const float* __restrict__ weight, const int* __restrict__ idxi,
                            float* __restrict__ oout) {
  __shared__ float tile[32][257];
  __shared__ int ids[32];
  const int b = blockIdx.y, t0 = blockIdx.x << 5;
  const int lane = threadIdx.x & 63, wave = threadIdx.x >> 6;
  if (threadIdx.x < 32) ids[threadIdx.x] = idxi[b * T_ + t0 + threadIdx.x] & 16383;
  __syncthreads();
  for (int i = 0; i < 8; ++i) {
    const int tl = (wave << 3) + i;
    const float4 v = reinterpret_cast<const float4*>(weight + (size_t)ids[tl] * D_)[lane];
    tile[tl][(lane << 2) + 0] = v.x;
    tile[tl][(lane << 2) + 1] = v.y;
    tile[tl][(lane << 2) + 2] = v.z;
    tile[tl][(lane << 2) + 3] = v.w;
  }
  __syncthreads();
  const int tp = threadIdx.x & 31, dg = threadIdx.x >> 5;
  for (int it = 0; it < 32; ++it) {
    const int d = (dg << 5) + it;
    oout[((size_t)b * D_ + d) * T_ + t0 + tp] = tile[tp][d];
  }
}

// ---------------- new_cluster_size + entropy + ntot ----------------
__global__ void k_fincnt_r8(const float* __restrict__ cs, const float* __restrict__ counts,
                            float* __restrict__ oncs, float* __restrict__ ent_acc,
                            float* __restrict__ ntot_acc) {
  __shared__ float red[8];
  const int n = blockIdx.x * 256 + threadIdx.x;
  const float c = counts[n];
  const float ncs = 0.99f * cs[n] + 0.01f * c;
  oncs[n] = ncs;
  const float p = c * (1.0f / 8192.0f);
  float se = p * logf(p + 1e-10f);
  float sn = ncs;
  for (int o = 32; o; o >>= 1) {
    se += __shfl_xor(se, o);
    sn += __shfl_xor(sn, o);
  }
  const int lane = threadIdx.x & 63, wave = threadIdx.x >> 6;
  if (lane == 0) { red[wave] = se; red[4 + wave] = sn; }
  __syncthreads();
  if (threadIdx.x == 0) {
    atomicAdd(ent_acc, red[0] + red[1] + red[2] + red[3]);
    atomicAdd(ntot_acc, red[4] + red[5] + red[6] + red[7]);
  }
}

// ---- new_weight = new_embed_avg / smoothed; fused scalar outputs ----
__global__ void k_finw_r14(const float* __restrict__ cs, const float* __restrict__ counts,
                           const float* __restrict__ ntot_acc,
                           const float* __restrict__ onea, float* __restrict__ oneww,
                           const float* __restrict__ loss_acc,
                           const float* __restrict__ ent_acc,
                           float* __restrict__ operp, float* __restrict__ oloss) {
  const int n = blockIdx.x;
  const int dl = threadIdx.x << 1;
  const float2 a = *reinterpret_cast<const float2*>(onea + (size_t)n * D_ + dl);
  const float ncs = 0.99f * cs[n] + 0.01f * counts[n];
  const float ntot = *ntot_acc;
  const float sm = (ncs + 1e-5f) / (ntot + N_ * 1e-5f) * ntot;
  float2 ow;
  ow.x = a.x / sm;
  ow.y = a.y / sm;
  *reinterpret_cast<float2*>(oneww + (size_t)n * D_ + dl) = ow;
  if (n == 0 && threadIdx.x == 0) {
    *operp = expf(-*ent_acc);
    *oloss = 0.25f * (*loss_acc) * (1.0f / 2097152.0f);
  }
}

extern "C" void kernel_launch(void* const* d_in, const int* in_sizes, int n_in,
                              void* d_out, int out_size, void* d_ws, size_t ws_size,
                              hipStream_t stream) {
  (void)in_sizes; (void)n_in; (void)out_size; (void)ws_size;
  const float* z = (const float*)d_in[0];
  const float* weight = (const float*)d_in[1];
  const float* cs = (const float*)d_in[2];
  const float* ea = (const float*)d_in[3];
  float* out = (float*)d_out;
  char* ws = (char*)d_ws;

  float* counts = (float*)(ws + W_CNT);
  float* scal = (float*)(ws + W_SCAL);
  float* w2 = (float*)(ws + W_W2);
  int* idxi = (int*)(ws + W_IDXI);
  unsigned long long* pack = (unsigned long long*)(ws + W_PACK);
  _Float16* zh = (_Float16*)(ws + W_ZH);
  _Float16* wh = (_Float16*)(ws + W_WH);
  float* zt = (float*)(ws + W_ZT);

  hipMemsetAsync(ws + W_CNT, 0, 65792, stream);  // counts + scalars

  hipLaunchKernelGGL(k_prepz_r14, dim3(16, 4, 8), dim3(256), 0, stream, z, zh, zt,
                     ea, out + O_NEA);
  hipLaunchKernelGGL(k_prepw_r8, dim3(N_ / 4), dim3(256), 0, stream, weight, wh, w2);
  hipLaunchKernelGGL(k_dist_r14, dim3(64, 8), dim3(1024), 0, stream, zh, wh, w2, pack);
  hipLaunchKernelGGL(k_cand_r15, dim3(BT_ / 4), dim3(256), 0, stream, zt, weight, pack,
                     idxi, counts, out + O_IDX, scal + 0, out + O_NEA);
  hipLaunchKernelGGL(k_gather_r8, dim3(32, 8), dim3(256), 0, stream, weight, idxi, out + O_OUT);
  hipLaunchKernelGGL(k_fincnt_r8, dim3(64), dim3(256), 0, stream, cs, counts, out + O_NCS,
                     scal + 1, scal + 2);
  hipLaunchKernelGGL(k_finw_r14, dim3(N_), dim3(128), 0, stream, cs, counts, scal + 2,
                     out + O_NEA, out + O_NEWW, scal + 0, scal + 1,
                     out + O_PERP, out + O_LOSS);
}

// Round 8
// 257.221 us; speedup vs baseline: 1.0322x; 1.0322x over previous
//
#include <hip/hip_runtime.h>
#include <hip/hip_bf16.h>

// EMAVectorQuantizer: B=8, D=256, T=1024, BT=8192, N=16384
// Outputs (FLOAT32, concat): out[B,D,T], perplexity, idx[BT], loss,
// new_weight[N,D], new_cluster_size[N], new_embed_avg[N,D] = 10,510,338 f32

#define B_ 8
#define D_ 256
#define T_ 1024
#define BT_ 8192
#define N_ 16384

// d_out element offsets (float32 elements)
#define O_OUT   0
#define O_PERP  2097152
#define O_IDX   2097153
#define O_LOSS  2105345
#define O_NEWW  2105346
#define O_NCS   6299650
#define O_NEA   6316034

// workspace byte offsets (ends ~21.2 MiB; prior session verified ws >= 25 MB)
#define W_CNT   0ull        // counts[N] f32 (zeroed)
#define W_SCAL  65536ull    // scalars: [0]=loss_sum [1]=ent [2]=ntot (zeroed)
#define W_W2    98560ull    // w2[N] f32
#define W_IDXI  164096ull   // idx int32[BT]
#define W_PACK  196864ull   // pack[BT][8] u64 candidates (512 KB, fully written)
#define W_ZH    1245440ull  // zh[BT][D] fp16, transposed z (4 MB)
#define W_WH    5439744ull  // wh[N][D] fp16 (8 MB)
#define W_ZT    13828352ull // zt[BT][D] f32, transposed z (8 MB) for exact re-rank

typedef __attribute__((ext_vector_type(8))) _Float16 half8;
typedef __attribute__((ext_vector_type(4))) _Float16 half4;
typedef __attribute__((ext_vector_type(4))) float f32x4;

__device__ __forceinline__ void gl_lds(const void* g, void* l) {
  __builtin_amdgcn_global_load_lds(
      (const __attribute__((address_space(1))) unsigned int*)g,
      (__attribute__((address_space(3))) unsigned int*)l, 16, 0, 0);
}

// monotone unsigned key for float compare (handles negative d = w2/2 - dot)
__device__ __forceinline__ unsigned sortable(float f) {
  unsigned u = __float_as_uint(f);
  return u ^ (((unsigned)((int)u >> 31)) | 0x80000000u);
}

// ---- prep z: transpose to zh fp16 + zt f32; fused new_embed_avg init ----
__global__ void k_prepz_r14(const float* __restrict__ z, _Float16* __restrict__ zh,
                            float* __restrict__ zt, const float* __restrict__ ea,
                            float* __restrict__ onea) {
  __shared__ float tile[64][65];
  const int t0 = blockIdx.x << 6, d0 = blockIdx.y << 6, b = blockIdx.z;
  const int tt = threadIdx.x & 63, q = threadIdx.x >> 6;
  for (int i = 0; i < 16; ++i) {
    const int dd = q + (i << 2);
    tile[tt][dd] = z[((size_t)b * D_ + d0 + dd) * T_ + t0 + tt];
  }
  // fused: onea = 0.99*ea (512 blocks x 256 thr x 8 float4 = N*D floats)
  const int bid = blockIdx.x + (blockIdx.y << 4) + (blockIdx.z << 6);
  const float4* eav = reinterpret_cast<const float4*>(ea);
  float4* ov = reinterpret_cast<float4*>(onea);
#pragma unroll
  for (int i = 0; i < 8; ++i) {
    const int idx = (bid << 11) + (i << 8) + threadIdx.x;
    const float4 v = eav[idx];
    float4 o;
    o.x = 0.99f * v.x; o.y = 0.99f * v.y; o.z = 0.99f * v.z; o.w = 0.99f * v.w;
    ov[idx] = o;
  }
  __syncthreads();
  for (int i = 0; i < 16; ++i) {
    const int ttw = q + (i << 2);
    const float v = tile[ttw][tt];
    const size_t off = ((size_t)(b * T_ + t0 + ttw)) * D_ + d0 + tt;
    zh[off] = (_Float16)v;
    zt[off] = v;
  }
}

// ---- prep w: wh[N][D] fp16 + w2 (wave per row) ----
__global__ void k_prepw_r8(const float* __restrict__ w, _Float16* __restrict__ wh,
                           float* __restrict__ w2) {
  const int row = blockIdx.x * 4 + (threadIdx.x >> 6);
  const int lane = threadIdx.x & 63;
  const float4 v = reinterpret_cast<const float4*>(w + (size_t)row * D_)[lane];
  half4 h;
  h[0] = (_Float16)v.x; h[1] = (_Float16)v.y; h[2] = (_Float16)v.z; h[3] = (_Float16)v.w;
  *reinterpret_cast<half4*>(wh + (size_t)row * D_ + (lane << 2)) = h;
  float s = v.x * v.x + v.y * v.y + v.z * v.z + v.w * v.w;
  for (int o = 32; o; o >>= 1) s += __shfl_xor(s, o);
  if (lane == 0) w2[row] = s;
}

// ---- fp16 MFMA distance GEMM + top-2 per (row, 4096-col slice) ----
// grid (64 rowblocks of 128, 4 cy) = 256 blocks = EXACTLY 1/CU single pass
// (was 2 sequential passes at cy=8: double A-stage, prologue, merge).
// 1024 thr = 16 waves (4 row-groups x 4 col-groups), wave = 32 rows x 64 cols;
// ct = 16 col-tiles of 256. A-RESIDENT: 128x256 A panel staged once (64 KB),
// rounds stage only B (32 KB), plain __syncthreads double-buffer on B.
// LDS swizzle: slot (m,c) holds source chunk c ^ (m&7).
__global__ __launch_bounds__(1024, 4) void k_dist_r16(
    const _Float16* __restrict__ zh, const _Float16* __restrict__ wh,
    const float* __restrict__ w2, unsigned long long* __restrict__ pack) {
  __shared__ _Float16 Asr[4][8192];   // resident A: 4 kc x (128 rows x 64 k) = 64 KB
  __shared__ _Float16 Bs[2][16384];   // B dbuf: 2 x (256 rows x 64 k) = 64 KB
  __shared__ unsigned long long Ms[4][128][2];  // cross-col-group merge (8 KB)

  const int tid = threadIdx.x;
  const int lane = tid & 63, w = tid >> 6;
  const int quad = lane >> 4, l15 = lane & 15;
  const int r0 = blockIdx.x << 7;
  const int cy = blockIdx.y;
  const int nbase = cy << 12;      // 4 slices of 4096 codes
  const int wrow = (w & 3) << 5;   // 4 row-groups x 32 rows
  const int wcol = (w >> 2) << 6;  // 4 col-groups x 64 cols

  // A staging: thread covers slot tid of each kc chunk (1024 slots/chunk)
  const int m_a = tid >> 3, cg_a = (tid & 7) ^ ((tid >> 3) & 7);
#pragma unroll
  for (int kc = 0; kc < 4; ++kc)
    gl_lds(zh + (((size_t)(r0 + m_a)) << 8) + (kc << 6) + (cg_a << 3),
           &Asr[kc][tid << 3]);

  // B staging geometry: thread covers slots tid and tid+1024 (2048 slots)
  int smb[2], scb[2];
#pragma unroll
  for (int j = 0; j < 2; ++j) {
    const int s = tid + (j << 10);
    smb[j] = s >> 3;
    scb[j] = (s & 7) ^ (smb[j] & 7);
  }
  // prologue: stage B(ct=0, kc=0) into buffer 0
#pragma unroll
  for (int j = 0; j < 2; ++j)
    gl_lds(wh + (((size_t)(nbase + smb[j])) << 8) + (scb[j] << 3),
           &Bs[0][(tid + (j << 10)) << 3]);

  float rd0[8], rd1[8];
  int ri0[8], ri1[8];
#pragma unroll
  for (int s = 0; s < 8; ++s) { rd0[s] = 3.0e38f; rd1[s] = 3.0e38f; ri0[s] = 0; ri1[s] = 0; }

  f32x4 acc[2][4];
  float w2h[4];

#pragma unroll 1
  for (int ct = 0; ct < 16; ++ct) {
    const int n0 = nbase + (ct << 8);
#pragma unroll
    for (int kc = 0; kc < 4; ++kc) {
      const int cur = kc & 1;  // static after unroll
      __syncthreads();
      if (kc < 3) {
        const int kb = (kc + 1) << 6;
#pragma unroll
        for (int j = 0; j < 2; ++j)
          gl_lds(wh + (((size_t)(n0 + smb[j])) << 8) + kb + (scb[j] << 3),
                 &Bs[cur ^ 1][(tid + (j << 10)) << 3]);
      } else if (ct < 15) {  // next ct, kc=0
        const int n0n = n0 + 256;
#pragma unroll
        for (int j = 0; j < 2; ++j)
          gl_lds(wh + (((size_t)(n0n + smb[j])) << 8) + (scb[j] << 3),
                 &Bs[cur ^ 1][(tid + (j << 10)) << 3]);
      }
      if (kc == 0) {
#pragma unroll
        for (int cf = 0; cf < 4; ++cf) w2h[cf] = 0.5f * w2[n0 + wcol + cf * 16 + l15];
#pragma unroll
        for (int i = 0; i < 2; ++i)
#pragma unroll
          for (int j = 0; j < 4; ++j) acc[i][j] = (f32x4)(0.f);
      }
#pragma unroll
      for (int kl = 0; kl < 2; ++kl) {  // 2 x K=32
        const int k8 = (kl << 2) + quad;
        half8 af[2], bf[4];
#pragma unroll
        for (int rf = 0; rf < 2; ++rf) {
          const int m = wrow + rf * 16 + l15;
          af[rf] = *reinterpret_cast<const half8*>(&Asr[kc][(m << 6) + ((k8 ^ (m & 7)) << 3)]);
        }
#pragma unroll
        for (int cf = 0; cf < 4; ++cf) {
          const int n = wcol + cf * 16 + l15;
          bf[cf] = *reinterpret_cast<const half8*>(&Bs[cur][(n << 6) + ((k8 ^ (n & 7)) << 3)]);
        }
#pragma unroll
        for (int rf = 0; rf < 2; ++rf)
#pragma unroll
          for (int cf = 0; cf < 4; ++cf)
            acc[rf][cf] = __builtin_amdgcn_mfma_f32_16x16x32_f16(af[rf], bf[cf], acc[rf][cf], 0, 0, 0);
      }
      if (kc == 3) {
        // key = w2/2 - dot (per-row z2/2 constant dropped; ordering unchanged)
#pragma unroll
        for (int rf = 0; rf < 2; ++rf)
#pragma unroll
          for (int cf = 0; cf < 4; ++cf) {
            const int idxv = n0 + wcol + cf * 16 + l15;
#pragma unroll
            for (int rg = 0; rg < 4; ++rg) {
              const int s = rf * 4 + rg;
              const float d = w2h[cf] - acc[rf][cf][rg];
              if (d < rd1[s]) {
                if (d < rd0[s]) { rd1[s] = rd0[s]; ri1[s] = ri0[s]; rd0[s] = d; ri0[s] = idxv; }
                else { rd1[s] = d; ri1[s] = idxv; }
              }
            }
          }
      }
    }
  }

  // merge top-2 across the 16 col-lanes of each quad (xor stays within quad).
#pragma unroll
  for (int s = 0; s < 8; ++s) {
    unsigned long long p0 = ((unsigned long long)sortable(rd0[s]) << 32) | (unsigned int)ri0[s];
    unsigned long long p1 = ((unsigned long long)sortable(rd1[s]) << 32) | (unsigned int)ri1[s];
    for (int off = 1; off < 16; off <<= 1) {
      const unsigned long long q0 = __shfl_xor(p0, off);
      const unsigned long long q1 = __shfl_xor(p1, off);
      const unsigned long long lo = p0 < q0 ? p0 : q0;
      const unsigned long long mx = p0 < q0 ? q0 : p0;
      const unsigned long long mn1 = p1 < q1 ? p1 : q1;
      p0 = lo;
      p1 = mx < mn1 ? mx : mn1;
    }
    if (l15 == 0) {
      const int row = wrow + (s >> 2) * 16 + quad * 4 + (s & 3);
      Ms[w >> 2][row][0] = p0;
      Ms[w >> 2][row][1] = p1;
    }
  }
  __syncthreads();
  // merge the four col-group slices -> top-2 per (row, cy)
  if (tid < 128) {
    unsigned long long p0 = Ms[0][tid][0], p1 = Ms[0][tid][1];
#pragma unroll
    for (int g = 1; g < 4; ++g) {
      const unsigned long long q0 = Ms[g][tid][0], q1 = Ms[g][tid][1];
      const unsigned long long n0_ = p0 < q0 ? p0 : q0;
      const unsigned long long n1_ = p0 < q0 ? (p1 < q0 ? p1 : q0) : (q1 < p0 ? q1 : p0);
      p0 = n0_;
      p1 = n1_;
    }
    unsigned long long* dst = pack + (((size_t)(r0 + tid)) << 3) + (cy << 1);
    dst[0] = p0;
    dst[1] = p1;
  }
}

// ---- fp64 re-rank of 8 candidates; idx + counts + loss + FUSED SCATTER ----
// wave per row; 4 x 16-lane groups re-rank 2 candidates each in parallel.
__global__ void k_cand_r16(const float* __restrict__ zt, const float* __restrict__ weight,
                           const unsigned long long* __restrict__ pack,
                           int* __restrict__ idxi, float* __restrict__ counts,
                           float* __restrict__ oidx, float* __restrict__ loss_acc,
                           float* __restrict__ onea) {
  __shared__ float lred[4];
  const int wv_ = threadIdx.x >> 6;
  const int row = blockIdx.x * 4 + wv_;
  const int lane = threadIdx.x & 63;
  const int g = lane >> 4, l = lane & 15;

  float4 zc[4];
#pragma unroll
  for (int q = 0; q < 4; ++q)
    zc[q] = reinterpret_cast<const float4*>(zt + (size_t)row * D_)[(q << 4) + l];

  double best = 1.0e300;
  int bestid = 0x7FFFFFFF;
#pragma unroll
  for (int c = 0; c < 2; ++c) {
    const int cand = (int)(pack[((size_t)row << 3) + (g << 1) + c] & 0xFFFFFFFFull) & 16383;
    double s = 0.0;
#pragma unroll
    for (int q = 0; q < 4; ++q) {
      const float4 wvv = reinterpret_cast<const float4*>(weight + (size_t)cand * D_)[(q << 4) + l];
      const double d0 = (double)zc[q].x - (double)wvv.x;
      const double d1 = (double)zc[q].y - (double)wvv.y;
      const double d2 = (double)zc[q].z - (double)wvv.z;
      const double d3 = (double)zc[q].w - (double)wvv.w;
      s = fma(d0, d0, s); s = fma(d1, d1, s); s = fma(d2, d2, s); s = fma(d3, d3, s);
    }
    for (int o = 1; o < 16; o <<= 1) s += __shfl_xor(s, o);
    if (s < best || (s == best && cand < bestid)) { best = s; bestid = cand; }
  }
#pragma unroll
  for (int o = 16; o < 64; o <<= 1) {
    const double os = __shfl_xor(best, o);
    const int oi = __shfl_xor(bestid, o);
    if (os < best || (os == best && oi < bestid)) { best = os; bestid = oi; }
  }
  // fused scatter: group g covers d = g*64 + l*4 .. +3 with zc[g]
  {
    float* dst = onea + (size_t)bestid * D_ + (g << 6) + (l << 2);
    atomicAdd(dst + 0, 0.01f * zc[g].x);
    atomicAdd(dst + 1, 0.01f * zc[g].y);
    atomicAdd(dst + 2, 0.01f * zc[g].z);
    atomicAdd(dst + 3, 0.01f * zc[g].w);
  }
  if (lane == 0) {
    idxi[row] = bestid;
    oidx[row] = (float)bestid;
    atomicAdd(&counts[bestid], 1.0f);
    lred[wv_] = (float)best;
  }
  __syncthreads();
  if (threadIdx.x == 0)
    atomicAdd(loss_acc, lred[0] + lred[1] + lred[2] + lred[3]);
}

// ---------------- gather codebook rows -> out[B,D,T] (f32) ----------------
__global__ void k_gather_r8(const float* __restrict__ weight, const int* __restrict__ idxi,
                            float* __restrict__ oout) {
  __shared__ float tile[32][257];
  __shared__ int ids[32];
  const int b = blockIdx.y, t0 = blockIdx.x << 5;
  const int lane = threadIdx.x & 63, wave = threadIdx.x >> 6;
  if (threadIdx.x < 32) ids[threadIdx.x] = idxi[b * T_ + t0 + threadIdx.x] & 16383;
  __syncthreads();
  for (int i = 0; i < 8; ++i) {
    const int tl = (wave << 3) + i;
    const float4 v = reinterpret_cast<const float4*>(weight + (size_t)ids[tl] * D_)[lane];
    tile[tl][(lane << 2) + 0] = v.x;
    tile[tl][(lane << 2) + 1] = v.y;
    tile[tl][(lane << 2) + 2] = v.z;
    tile[tl][(lane << 2) + 3] = v.w;
  }
  __syncthreads();
  const int tp = threadIdx.x & 31, dg = threadIdx.x >> 5;
  for (int it = 0; it < 32; ++it) {
    const int d = (dg << 5) + it;
    oout[((size_t)b * D_ + d) * T_ + t0 + tp] = tile[tp][d];
  }
}

// ---------------- new_cluster_size + entropy + ntot ----------------
__global__ void k_fincnt_r8(const float* __restrict__ cs, const float* __restrict__ counts,
                            float* __restrict__ oncs, float* __restrict__ ent_acc,
                            float* __restrict__ ntot_acc) {
  __shared__ float red[8];
  const int n = blockIdx.x * 256 + threadIdx.x;
  const float c = counts[n];
  const float ncs = 0.99f * cs[n] + 0.01f * c;
  oncs[n] = ncs;
  const float p = c * (1.0f / 8192.0f);
  float se = p * logf(p + 1e-10f);
  float sn = ncs;
  for (int o = 32; o; o >>= 1) {
    se += __shfl_xor(se, o);
    sn += __shfl_xor(sn, o);
  }
  const int lane = threadIdx.x & 63, wave = threadIdx.x >> 6;
  if (lane == 0) { red[wave] = se; red[4 + wave] = sn; }
  __syncthreads();
  if (threadIdx.x == 0) {
    atomicAdd(ent_acc, red[0] + red[1] + red[2] + red[3]);
    atomicAdd(ntot_acc, red[4] + red[5] + red[6] + red[7]);
  }
}

// ---- new_weight = new_embed_avg / smoothed; fused scalar outputs ----
__global__ void k_finw_r14(const float* __restrict__ cs, const float* __restrict__ counts,
                           const float* __restrict__ ntot_acc,
                           const float* __restrict__ onea, float* __restrict__ oneww,
                           const float* __restrict__ loss_acc,
                           const float* __restrict__ ent_acc,
                           float* __restrict__ operp, float* __restrict__ oloss) {
  const int n = blockIdx.x;
  const int dl = threadIdx.x << 1;
  const float2 a = *reinterpret_cast<const float2*>(onea + (size_t)n * D_ + dl);
  const float ncs = 0.99f * cs[n] + 0.01f * counts[n];
  const float ntot = *ntot_acc;
  const float sm = (ncs + 1e-5f) / (ntot + N_ * 1e-5f) * ntot;
  float2 ow;
  ow.x = a.x / sm;
  ow.y = a.y / sm;
  *reinterpret_cast<float2*>(oneww + (size_t)n * D_ + dl) = ow;
  if (n == 0 && threadIdx.x == 0) {
    *operp = expf(-*ent_acc);
    *oloss = 0.25f * (*loss_acc) * (1.0f / 2097152.0f);
  }
}

extern "C" void kernel_launch(void* const* d_in, const int* in_sizes, int n_in,
                              void* d_out, int out_size, void* d_ws, size_t ws_size,
                              hipStream_t stream) {
  (void)in_sizes; (void)n_in; (void)out_size; (void)ws_size;
  const float* z = (const float*)d_in[0];
  const float* weight = (const float*)d_in[1];
  const float* cs = (const float*)d_in[2];
  const float* ea = (const float*)d_in[3];
  float* out = (float*)d_out;
  char* ws = (char*)d_ws;

  float* counts = (float*)(ws + W_CNT);
  float* scal = (float*)(ws + W_SCAL);
  float* w2 = (float*)(ws + W_W2);
  int* idxi = (int*)(ws + W_IDXI);
  unsigned long long* pack = (unsigned long long*)(ws + W_PACK);
  _Float16* zh = (_Float16*)(ws + W_ZH);
  _Float16* wh = (_Float16*)(ws + W_WH);
  float* zt = (float*)(ws + W_ZT);

  hipMemsetAsync(ws + W_CNT, 0, 65792, stream);  // counts + scalars

  hipLaunchKernelGGL(k_prepz_r14, dim3(16, 4, 8), dim3(256), 0, stream, z, zh, zt,
                     ea, out + O_NEA);
  hipLaunchKernelGGL(k_prepw_r8, dim3(N_ / 4), dim3(256), 0, stream, weight, wh, w2);
  hipLaunchKernelGGL(k_dist_r16, dim3(64, 4), dim3(1024), 0, stream, zh, wh, w2, pack);
  hipLaunchKernelGGL(k_cand_r16, dim3(BT_ / 4), dim3(256), 0, stream, zt, weight, pack,
                     idxi, counts, out + O_IDX, scal + 0, out + O_NEA);
  hipLaunchKernelGGL(k_gather_r8, dim3(32, 8), dim3(256), 0, stream, weight, idxi, out + O_OUT);
  hipLaunchKernelGGL(k_fincnt_r8, dim3(64), dim3(256), 0, stream, cs, counts, out + O_NCS,
                     scal + 1, scal + 2);
  hipLaunchKernelGGL(k_finw_r14, dim3(N_), dim3(128), 0, stream, cs, counts, scal + 2,
                     out + O_NEA, out + O_NEWW, scal + 0, scal + 1,
                     out + O_PERP, out + O_LOSS);
}

// Round 9
// 251.157 us; speedup vs baseline: 1.0571x; 1.0241x over previous
//
#include <hip/hip_runtime.h>
#include <hip/hip_bf16.h>

// EMAVectorQuantizer: B=8, D=256, T=1024, BT=8192, N=16384
// Outputs (FLOAT32, concat): out[B,D,T], perplexity, idx[BT], loss,
// new_weight[N,D], new_cluster_size[N], new_embed_avg[N,D] = 10,510,338 f32

#define B_ 8
#define D_ 256
#define T_ 1024
#define BT_ 8192
#define N_ 16384

// d_out element offsets (float32 elements)
#define O_OUT   0
#define O_PERP  2097152
#define O_IDX   2097153
#define O_LOSS  2105345
#define O_NEWW  2105346
#define O_NCS   6299650
#define O_NEA   6316034

// workspace byte offsets (ends ~21.2 MiB; prior session verified ws >= 25 MB)
#define W_CNT   0ull        // counts[N] f32 (zeroed in k_prep)
#define W_SCAL  65536ull    // scalars: [0]=loss_sum [1]=ent [2]=ntot (zeroed)
#define W_W2    98560ull    // w2[N] f32
#define W_IDXI  164096ull   // idx int32[BT]
#define W_PACK  196864ull   // pack[BT][8] u64 candidates (512 KB, fully written)
#define W_ZH    1245440ull  // zh[BT][D] fp16, transposed z (4 MB)
#define W_WH    5439744ull  // wh[N][D] fp16 (8 MB)
#define W_ZT    13828352ull // zt[BT][D] f32, transposed z (8 MB) for exact re-rank

typedef __attribute__((ext_vector_type(8))) _Float16 half8;
typedef __attribute__((ext_vector_type(4))) _Float16 half4;
typedef __attribute__((ext_vector_type(4))) float f32x4;

__device__ __forceinline__ void gl_lds(const void* g, void* l) {
  __builtin_amdgcn_global_load_lds(
      (const __attribute__((address_space(1))) unsigned int*)g,
      (__attribute__((address_space(3))) unsigned int*)l, 16, 0, 0);
}

// monotone unsigned key for float compare (handles negative d = w2/2 - dot)
__device__ __forceinline__ unsigned sortable(float f) {
  unsigned u = __float_as_uint(f);
  return u ^ (((unsigned)((int)u >> 31)) | 0x80000000u);
}

// ---- fused prep: [0,4096) prepw (+zero-init), [4096,4608) prepz ----
__global__ void k_prep_r17(const float* __restrict__ z, _Float16* __restrict__ zh,
                           float* __restrict__ zt, const float* __restrict__ ea,
                           float* __restrict__ onea, const float* __restrict__ wt,
                           _Float16* __restrict__ wh, float* __restrict__ w2,
                           float* __restrict__ zero0) {
  __shared__ float tile[64][65];
  const int bid = blockIdx.x;
  if (bid < 4096) {
    // zero counts+scalars: 16448 floats over first 65 blocks
    if (bid < 65) {
      const int off = (bid << 8) + threadIdx.x;
      if (off < 16448) zero0[off] = 0.f;
    }
    // prepw: wh fp16 + w2 (wave per row)
    const int row = (bid << 2) + (threadIdx.x >> 6);
    const int lane = threadIdx.x & 63;
    const float4 v = reinterpret_cast<const float4*>(wt + (size_t)row * D_)[lane];
    half4 h;
    h[0] = (_Float16)v.x; h[1] = (_Float16)v.y; h[2] = (_Float16)v.z; h[3] = (_Float16)v.w;
    *reinterpret_cast<half4*>(wh + (size_t)row * D_ + (lane << 2)) = h;
    float s = v.x * v.x + v.y * v.y + v.z * v.z + v.w * v.w;
    for (int o = 32; o; o >>= 1) s += __shfl_xor(s, o);
    if (lane == 0) w2[row] = s;
  } else {
    // prepz: transpose to zh fp16 + zt f32; fused onea = 0.99*ea
    const int bid2 = bid - 4096;
    const int t0 = (bid2 & 15) << 6, d0 = ((bid2 >> 4) & 3) << 6, b = bid2 >> 6;
    const int tt = threadIdx.x & 63, q = threadIdx.x >> 6;
    for (int i = 0; i < 16; ++i) {
      const int dd = q + (i << 2);
      tile[tt][dd] = z[((size_t)b * D_ + d0 + dd) * T_ + t0 + tt];
    }
    const float4* eav = reinterpret_cast<const float4*>(ea);
    float4* ov = reinterpret_cast<float4*>(onea);
#pragma unroll
    for (int i = 0; i < 8; ++i) {
      const int idx = (bid2 << 11) + (i << 8) + threadIdx.x;
      const float4 v = eav[idx];
      float4 o;
      o.x = 0.99f * v.x; o.y = 0.99f * v.y; o.z = 0.99f * v.z; o.w = 0.99f * v.w;
      ov[idx] = o;
    }
    __syncthreads();
    for (int i = 0; i < 16; ++i) {
      const int ttw = q + (i << 2);
      const float v = tile[ttw][tt];
      const size_t off = ((size_t)(b * T_ + t0 + ttw)) * D_ + d0 + tt;
      zh[off] = (_Float16)v;
      zt[off] = v;
    }
  }
}

// ---- fp16 MFMA distance GEMM + top-2 per (row, 4096-col slice) ----
// grid (64 rowblocks of 128, 4 cy) = 256 blocks = 1/CU single pass.
// 1024 thr = 16 waves (4 rg x 4 cg), wave = 32 rows x 64 cols; ct = 16 x 256.
// r17: IMMEDIATE-OFFSET ADDRESSING. Flat SA/SB; per-thread read bases
// A0/A1/B0/B1 (m&7 == l15&7 since wrow,rf*16,wcol,cf*16 are 0 mod 8), all
// round offsets (kc*8K, rf*1K, cur*16K, cf*1K elems) are unrolled constants
// -> ds_read_b128 base+imm, no per-round address VALU. B staging via running
// gB pointers (+65536 elems per ct) + constant offsets.
// Data layout/swizzle/schedule identical to r16.
__global__ __launch_bounds__(1024, 4) void k_dist_r17(
    const _Float16* __restrict__ zh, const _Float16* __restrict__ wh,
    const float* __restrict__ w2, unsigned long long* __restrict__ pack) {
  __shared__ _Float16 SA[32768];  // resident A: 4 kc regions x 8192 = 64 KB
  __shared__ _Float16 SB[32768];  // B dbuf: 2 regions x 16384 = 64 KB
  __shared__ unsigned long long Ms[4][128][2];  // cross-col-group merge (8 KB)

  const int tid = threadIdx.x;
  const int lane = tid & 63, w = tid >> 6;
  const int quad = lane >> 4, l15 = lane & 15;
  const int q7 = l15 & 7;
  const int r0 = blockIdx.x << 7;
  const int cy = blockIdx.y;
  const int nbase = cy << 12;      // 4 slices of 4096 codes
  const int wrow = (w & 3) << 5;   // 4 row-groups x 32 rows
  const int wcol = (w >> 2) << 6;  // 4 col-groups x 64 cols

  // per-thread LDS read bases (element units)
  const _Float16* A0 = SA + ((wrow + l15) << 6) + ((quad ^ q7) << 3);
  const _Float16* A1 = SA + ((wrow + l15) << 6) + (((quad + 4) ^ q7) << 3);
  const _Float16* B0 = SB + ((wcol + l15) << 6) + ((quad ^ q7) << 3);
  const _Float16* B1 = SB + ((wcol + l15) << 6) + (((quad + 4) ^ q7) << 3);

  // A staging (once): thread covers slot tid of each kc chunk
  {
    const int m_a = tid >> 3, cg_a = (tid & 7) ^ ((tid >> 3) & 7);
    const _Float16* gA = zh + (((size_t)(r0 + m_a)) << 8) + (cg_a << 3);
    _Float16* lA = SA + (tid << 3);
#pragma unroll
    for (int kc = 0; kc < 4; ++kc)
      gl_lds(gA + (kc << 6), lA + (kc << 13));
  }

  // B staging geometry: slots tid and tid+1024; running global base per ct
  const int smb0 = tid >> 3, scb0 = (tid & 7) ^ (smb0 & 7);
  const int s1 = tid + 1024;
  const int smb1 = s1 >> 3, scb1 = (s1 & 7) ^ (smb1 & 7);
  const _Float16* gB0 = wh + (((size_t)(nbase + smb0)) << 8) + (scb0 << 3);
  const _Float16* gB1 = wh + (((size_t)(nbase + smb1)) << 8) + (scb1 << 3);
  _Float16* lB0 = SB + (tid << 3);
  _Float16* lB1 = SB + (s1 << 3);

  // prologue: stage B(ct=0,kc=0) into region 0
  gl_lds(gB0, lB0);
  gl_lds(gB1, lB1);

  float rd0[8], rd1[8];
  int ri0[8], ri1[8];
#pragma unroll
  for (int s = 0; s < 8; ++s) { rd0[s] = 3.0e38f; rd1[s] = 3.0e38f; ri0[s] = 0; ri1[s] = 0; }

  f32x4 acc[2][4];
  float w2h[4];

#pragma unroll 1
  for (int ct = 0; ct < 16; ++ct) {
    const int n0 = nbase + (ct << 8);
#pragma unroll
    for (int kc = 0; kc < 4; ++kc) {
      const int cur = kc & 1;           // compile-time after unroll
      const int nxt = (cur ^ 1) << 14;  // LDS region for staged chunk (elems)
      __syncthreads();
      if (kc < 3) {
        gl_lds(gB0 + ((kc + 1) << 6), lB0 + nxt);
        gl_lds(gB1 + ((kc + 1) << 6), lB1 + nxt);
      } else if (ct < 15) {  // next ct, kc=0: +256 cols = +65536 elems
        gl_lds(gB0 + 65536, lB0 + nxt);
        gl_lds(gB1 + 65536, lB1 + nxt);
      }
      if (kc == 0) {
#pragma unroll
        for (int cf = 0; cf < 4; ++cf) w2h[cf] = 0.5f * w2[n0 + wcol + cf * 16 + l15];
#pragma unroll
        for (int i = 0; i < 2; ++i)
#pragma unroll
          for (int j = 0; j < 4; ++j) acc[i][j] = (f32x4)(0.f);
      }
      {
        const int cko = kc << 13;   // A kc region (elems), compile-time
        const int cbo = cur << 14;  // B cur region (elems), compile-time
#pragma unroll
        for (int kl = 0; kl < 2; ++kl) {
          const _Float16* Ak = kl ? A1 : A0;
          const _Float16* Bk = kl ? B1 : B0;
          half8 af[2], bf[4];
          af[0] = *reinterpret_cast<const half8*>(Ak + cko);
          af[1] = *reinterpret_cast<const half8*>(Ak + cko + 1024);
          bf[0] = *reinterpret_cast<const half8*>(Bk + cbo);
          bf[1] = *reinterpret_cast<const half8*>(Bk + cbo + 1024);
          bf[2] = *reinterpret_cast<const half8*>(Bk + cbo + 2048);
          bf[3] = *reinterpret_cast<const half8*>(Bk + cbo + 3072);
#pragma unroll
          for (int rf = 0; rf < 2; ++rf)
#pragma unroll
            for (int cf = 0; cf < 4; ++cf)
              acc[rf][cf] = __builtin_amdgcn_mfma_f32_16x16x32_f16(af[rf], bf[cf], acc[rf][cf], 0, 0, 0);
        }
      }
      if (kc == 3) {
        // key = w2/2 - dot (per-row z2/2 constant dropped; ordering unchanged)
#pragma unroll
        for (int rf = 0; rf < 2; ++rf)
#pragma unroll
          for (int cf = 0; cf < 4; ++cf) {
            const int idxv = n0 + wcol + cf * 16 + l15;
#pragma unroll
            for (int rg = 0; rg < 4; ++rg) {
              const int s = rf * 4 + rg;
              const float d = w2h[cf] - acc[rf][cf][rg];
              if (d < rd1[s]) {
                if (d < rd0[s]) { rd1[s] = rd0[s]; ri1[s] = ri0[s]; rd0[s] = d; ri0[s] = idxv; }
                else { rd1[s] = d; ri1[s] = idxv; }
              }
            }
          }
      }
    }
    gB0 += 65536;
    gB1 += 65536;
  }

  // merge top-2 across the 16 col-lanes of each quad (xor stays within quad).
#pragma unroll
  for (int s = 0; s < 8; ++s) {
    unsigned long long p0 = ((unsigned long long)sortable(rd0[s]) << 32) | (unsigned int)ri0[s];
    unsigned long long p1 = ((unsigned long long)sortable(rd1[s]) << 32) | (unsigned int)ri1[s];
    for (int off = 1; off < 16; off <<= 1) {
      const unsigned long long q0 = __shfl_xor(p0, off);
      const unsigned long long q1 = __shfl_xor(p1, off);
      const unsigned long long lo = p0 < q0 ? p0 : q0;
      const unsigned long long mx = p0 < q0 ? q0 : p0;
      const unsigned long long mn1 = p1 < q1 ? p1 : q1;
      p0 = lo;
      p1 = mx < mn1 ? mx : mn1;
    }
    if (l15 == 0) {
      const int row = wrow + (s >> 2) * 16 + quad * 4 + (s & 3);
      Ms[w >> 2][row][0] = p0;
      Ms[w >> 2][row][1] = p1;
    }
  }
  __syncthreads();
  // merge the four col-group slices -> top-2 per (row, cy)
  if (tid < 128) {
    unsigned long long p0 = Ms[0][tid][0], p1 = Ms[0][tid][1];
#pragma unroll
    for (int g = 1; g < 4; ++g) {
      const unsigned long long q0 = Ms[g][tid][0], q1 = Ms[g][tid][1];
      const unsigned long long n0_ = p0 < q0 ? p0 : q0;
      const unsigned long long n1_ = p0 < q0 ? (p1 < q0 ? p1 : q0) : (q1 < p0 ? q1 : p0);
      p0 = n0_;
      p1 = n1_;
    }
    unsigned long long* dst = pack + (((size_t)(r0 + tid)) << 3) + (cy << 1);
    dst[0] = p0;
    dst[1] = p1;
  }
}

// ---- fp64 re-rank of 8 candidates; idx + counts + loss + fused scatter ----
__global__ void k_cand_r16(const float* __restrict__ zt, const float* __restrict__ weight,
                           const unsigned long long* __restrict__ pack,
                           int* __restrict__ idxi, float* __restrict__ counts,
                           float* __restrict__ oidx, float* __restrict__ loss_acc,
                           float* __restrict__ onea) {
  __shared__ float lred[4];
  const int wv_ = threadIdx.x >> 6;
  const int row = blockIdx.x * 4 + wv_;
  const int lane = threadIdx.x & 63;
  const int g = lane >> 4, l = lane & 15;

  float4 zc[4];
#pragma unroll
  for (int q = 0; q < 4; ++q)
    zc[q] = reinterpret_cast<const float4*>(zt + (size_t)row * D_)[(q << 4) + l];

  double best = 1.0e300;
  int bestid = 0x7FFFFFFF;
#pragma unroll
  for (int c = 0; c < 2; ++c) {
    const int cand = (int)(pack[((size_t)row << 3) + (g << 1) + c] & 0xFFFFFFFFull) & 16383;
    double s = 0.0;
#pragma unroll
    for (int q = 0; q < 4; ++q) {
      const float4 wvv = reinterpret_cast<const float4*>(weight + (size_t)cand * D_)[(q << 4) + l];
      const double d0 = (double)zc[q].x - (double)wvv.x;
      const double d1 = (double)zc[q].y - (double)wvv.y;
      const double d2 = (double)zc[q].z - (double)wvv.z;
      const double d3 = (double)zc[q].w - (double)wvv.w;
      s = fma(d0, d0, s); s = fma(d1, d1, s); s = fma(d2, d2, s); s = fma(d3, d3, s);
    }
    for (int o = 1; o < 16; o <<= 1) s += __shfl_xor(s, o);
    if (s < best || (s == best && cand < bestid)) { best = s; bestid = cand; }
  }
#pragma unroll
  for (int o = 16; o < 64; o <<= 1) {
    const double os = __shfl_xor(best, o);
    const int oi = __shfl_xor(bestid, o);
    if (os < best || (os == best && oi < bestid)) { best = os; bestid = oi; }
  }
  // fused scatter: group g covers d = g*64 + l*4 .. +3 with zc[g]
  {
    float* dst = onea + (size_t)bestid * D_ + (g << 6) + (l << 2);
    atomicAdd(dst + 0, 0.01f * zc[g].x);
    atomicAdd(dst + 1, 0.01f * zc[g].y);
    atomicAdd(dst + 2, 0.01f * zc[g].z);
    atomicAdd(dst + 3, 0.01f * zc[g].w);
  }
  if (lane == 0) {
    idxi[row] = bestid;
    oidx[row] = (float)bestid;
    atomicAdd(&counts[bestid], 1.0f);
    lred[wv_] = (float)best;
  }
  __syncthreads();
  if (threadIdx.x == 0)
    atomicAdd(loss_acc, lred[0] + lred[1] + lred[2] + lred[3]);
}

// ---- fused post: [0,256) gather, [256,320) fincnt ----
__global__ void k_post_r17(const float* __restrict__ weight, const int* __restrict__ idxi,
                           float* __restrict__ oout, const float* __restrict__ cs,
                           const float* __restrict__ counts, float* __restrict__ oncs,
                           float* __restrict__ ent_acc, float* __restrict__ ntot_acc) {
  __shared__ float tile[32][257];
  __shared__ int ids[32];
  __shared__ float red[8];
  if (blockIdx.x < 256) {
    // gather codebook rows -> out[B,D,T]
    const int b = blockIdx.x >> 5, t0 = (blockIdx.x & 31) << 5;
    const int lane = threadIdx.x & 63, wave = threadIdx.x >> 6;
    if (threadIdx.x < 32) ids[threadIdx.x] = idxi[b * T_ + t0 + threadIdx.x] & 16383;
    __syncthreads();
    for (int i = 0; i < 8; ++i) {
      const int tl = (wave << 3) + i;
      const float4 v = reinterpret_cast<const float4*>(weight + (size_t)ids[tl] * D_)[lane];
      tile[tl][(lane << 2) + 0] = v.x;
      tile[tl][(lane << 2) + 1] = v.y;
      tile[tl][(lane << 2) + 2] = v.z;
      tile[tl][(lane << 2) + 3] = v.w;
    }
    __syncthreads();
    const int tp = threadIdx.x & 31, dg = threadIdx.x >> 5;
    for (int it = 0; it < 32; ++it) {
      const int d = (dg << 5) + it;
      oout[((size_t)b * D_ + d) * T_ + t0 + tp] = tile[tp][d];
    }
  } else {
    // new_cluster_size + entropy + ntot
    const int n = ((blockIdx.x - 256) << 8) + threadIdx.x;
    const float c = counts[n];
    const float ncs = 0.99f * cs[n] + 0.01f * c;
    oncs[n] = ncs;
    const float p = c * (1.0f / 8192.0f);
    float se = p * logf(p + 1e-10f);
    float sn = ncs;
    for (int o = 32; o; o >>= 1) {
      se += __shfl_xor(se, o);
      sn += __shfl_xor(sn, o);
    }
    const int lane = threadIdx.x & 63, wave = threadIdx.x >> 6;
    if (lane == 0) { red[wave] = se; red[4 + wave] = sn; }
    __syncthreads();
    if (threadIdx.x == 0) {
      atomicAdd(ent_acc, red[0] + red[1] + red[2] + red[3]);
      atomicAdd(ntot_acc, red[4] + red[5] + red[6] + red[7]);
    }
  }
}

// ---- new_weight = new_embed_avg / smoothed; fused scalar outputs ----
__global__ void k_finw_r14(const float* __restrict__ cs, const float* __restrict__ counts,
                           const float* __restrict__ ntot_acc,
                           const float* __restrict__ onea, float* __restrict__ oneww,
                           const float* __restrict__ loss_acc,
                           const float* __restrict__ ent_acc,
                           float* __restrict__ operp, float* __restrict__ oloss) {
  const int n = blockIdx.x;
  const int dl = threadIdx.x << 1;
  const float2 a = *reinterpret_cast<const float2*>(onea + (size_t)n * D_ + dl);
  const float ncs = 0.99f * cs[n] + 0.01f * counts[n];
  const float ntot = *ntot_acc;
  const float sm = (ncs + 1e-5f) / (ntot + N_ * 1e-5f) * ntot;
  float2 ow;
  ow.x = a.x / sm;
  ow.y = a.y / sm;
  *reinterpret_cast<float2*>(oneww + (size_t)n * D_ + dl) = ow;
  if (n == 0 && threadIdx.x == 0) {
    *operp = expf(-*ent_acc);
    *oloss = 0.25f * (*loss_acc) * (1.0f / 2097152.0f);
  }
}

extern "C" void kernel_launch(void* const* d_in, const int* in_sizes, int n_in,
                              void* d_out, int out_size, void* d_ws, size_t ws_size,
                              hipStream_t stream) {
  (void)in_sizes; (void)n_in; (void)out_size; (void)ws_size;
  const float* z = (const float*)d_in[0];
  const float* weight = (const float*)d_in[1];
  const float* cs = (const float*)d_in[2];
  const float* ea = (const float*)d_in[3];
  float* out = (float*)d_out;
  char* ws = (char*)d_ws;

  float* counts = (float*)(ws + W_CNT);
  float* scal = (float*)(ws + W_SCAL);
  float* w2 = (float*)(ws + W_W2);
  int* idxi = (int*)(ws + W_IDXI);
  unsigned long long* pack = (unsigned long long*)(ws + W_PACK);
  _Float16* zh = (_Float16*)(ws + W_ZH);
  _Float16* wh = (_Float16*)(ws + W_WH);
  float* zt = (float*)(ws + W_ZT);

  hipLaunchKernelGGL(k_prep_r17, dim3(4608), dim3(256), 0, stream, z, zh, zt,
                     ea, out + O_NEA, weight, wh, w2, (float*)(ws + W_CNT));
  hipLaunchKernelGGL(k_dist_r17, dim3(64, 4), dim3(1024), 0, stream, zh, wh, w2, pack);
  hipLaunchKernelGGL(k_cand_r16, dim3(BT_ / 4), dim3(256), 0, stream, zt, weight, pack,
                     idxi, counts, out + O_IDX, scal + 0, out + O_NEA);
  hipLaunchKernelGGL(k_post_r17, dim3(320), dim3(256), 0, stream, weight, idxi,
                     out + O_OUT, cs, counts, out + O_NCS, scal + 1, scal + 2);
  hipLaunchKernelGGL(k_finw_r14, dim3(N_), dim3(128), 0, stream, cs, counts, scal + 2,
                     out + O_NEA, out + O_NEWW, scal + 0, scal + 1,
                     out + O_PERP, out + O_LOSS);
}